// Round 5
// baseline (1623.739 us; speedup 1.0000x reference)
//
#include <hip/hip_runtime.h>

// ---------------------------------------------------------------------------
// RWA recurrent cell, MI355X — round 5.
// 256 blocks = 32 batches x 8 column-chunks, 512 threads (wave = feature).
// Sync design (lesson from r4: per-line fan-in is the knob):
//   - 16 leaf arrive counters (fan-in 16); wave 0 polls ALL 16 (no root/gen).
//   - BN stats: 16 replicas (fan-in 16/line), memory-side relaxed atomics.
//   - XR(t+1) prefetched at top of phase A (latency hidden under conv).
// ---------------------------------------------------------------------------

#define NBLK 256
#define NTHR 512

constexpr int Bb = 32, Tt = 128, NCc = 1024;
constexpr int PROW = 1032;       // padded XR row: [4 zeros][1024][4 zeros]
constexpr float EPSf  = 1e-5f;
constexpr float INV_N = 1.0f / 32768.0f;   // 1/(B*NC)

// workspace layout (floats)
constexpr size_t XR_OFF  = 0;
constexpr size_t XR_SZ   = (size_t)Tt * Bb * PROW;     // 4,227,072
constexpr size_t WT_OFF  = XR_OFF + XR_SZ;
constexpr size_t WT_SZ   = 131072;                     // [128][1024] W^T
constexpr size_t WPK_OFF = WT_OFF + WT_SZ;
constexpr size_t WPK_SZ  = 1280;                       // [8][10][16] packed conv w
constexpr size_t ACC_OFF = WPK_OFF + WPK_SZ;           // [3 par][16 rep][64][32]
constexpr size_t ACC_SZ  = 3 * 16 * 64 * 32;           // 98,304
constexpr size_t SL2_OFF = ACC_OFF + ACC_SZ;           // [2 par][32 bb][8 cc][2 side][64]
constexpr size_t SL2_SZ  = 2 * 32 * 8 * 2 * 64;        // 65,536
constexpr size_t CNT_OFF = SL2_OFF + SL2_SZ;           // 16 leaf counters, 128B apart

// output offsets (floats): (outs, s, n, d, h, a_max)
constexpr int OUT_S  = 32000;
constexpr int OUT_N  = 294144;
constexpr int OUT_D  = 556288;
constexpr int OUT_H  = 818432;
constexpr int OUT_AM = 1080576;

__device__ __forceinline__ float fast_tanh(float x) {
  float e = __expf(2.0f * x);
  return 1.0f - 2.0f / (e + 1.0f);
}

__device__ __forceinline__ unsigned long long pack2(float a, float b) {
  return (unsigned long long)__float_as_uint(a) |
         ((unsigned long long)__float_as_uint(b) << 32);
}

// ---------------------------------------------------------------------------
__global__ void prep_kernel(const float* __restrict__ w, float* __restrict__ wT,
                            const float* __restrict__ gw, const float* __restrict__ aw,
                            const float* __restrict__ dw, const float* __restrict__ uw,
                            float* __restrict__ wpack, float* __restrict__ acc3,
                            unsigned* __restrict__ cnt) {
  const int g = blockIdx.x * 256 + threadIdx.x;
  if (g < 131072) {
    const int c = g >> 7, k = g & 127;
    wT[k * 1024 + c] = w[g];
  }
  if (g < 1280) {
    const int f = g / 160, r = g % 160, ci = r >> 4, k = r & 15;
    float v = 0.f;
    if (ci < 9) {
      if (k < 5)       v = gw[(f * 9 + ci) * 5 + k];
      else if (k < 10) v = aw[(f * 9 + ci) * 5 + (k - 5)];
      else if (k < 15) v = dw[(f * 9 + ci) * 5 + (k - 10)];
    } else {
      if (k < 5)       v = uw[f * 5 + k];
    }
    wpack[g] = v;
  }
  if (g < (int)ACC_SZ) acc3[g] = 0.f;
  if (g < 1024) cnt[g] = 0u;
}

// ---------------------------------------------------------------------------
__global__ void __launch_bounds__(256) xr_kernel(const float* __restrict__ x,
                                                 const float* __restrict__ wT,
                                                 float* __restrict__ XR) {
  const int tb0 = blockIdx.x * 16;
  const int c0  = threadIdx.x * 4;
  float4 acc[16];
#pragma unroll
  for (int j = 0; j < 16; ++j) acc[j] = make_float4(0.f, 0.f, 0.f, 0.f);
#pragma unroll 4
  for (int k = 0; k < 128; ++k) {
    const float4 wv = *(const float4*)(wT + (size_t)k * 1024 + c0);
#pragma unroll
    for (int j = 0; j < 16; ++j) {
      const int tb = tb0 + j;
      const float xs = x[(size_t)(tb & 31) * 16384 + (size_t)(tb >> 5) * 128 + k];
      acc[j].x = fmaf(xs, wv.x, acc[j].x);
      acc[j].y = fmaf(xs, wv.y, acc[j].y);
      acc[j].z = fmaf(xs, wv.z, acc[j].z);
      acc[j].w = fmaf(xs, wv.w, acc[j].w);
    }
  }
#pragma unroll
  for (int j = 0; j < 16; ++j) {
    float* row = XR + (size_t)(tb0 + j) * PROW;
    *(float4*)(row + 4 + c0) = acc[j];
    if (threadIdx.x == 0)   { row[0] = row[1] = row[2] = row[3] = 0.f; }
    if (threadIdx.x == 255) { row[1028] = row[1029] = row[1030] = row[1031] = 0.f; }
  }
}

// ---------------------------------------------------------------------------
// scan: block=(bb,cc); wave=feature f; lane owns cols {2l, 2l+1} of chunk.
// ---------------------------------------------------------------------------
__global__ void __launch_bounds__(NTHR) scan_kernel(
    const float* __restrict__ XR, const float* __restrict__ wpack,
    float* acc3, float* slots2, unsigned* cnt,
    const float* __restrict__ s_in, const float* __restrict__ n_in,
    const float* __restrict__ d_in, const float* __restrict__ h_in,
    const float* __restrict__ am_in,
    const float* __restrict__ ggm, const float* __restrict__ gbt,
    const float* __restrict__ ugm, const float* __restrict__ ubt,
    const float* __restrict__ agm, const float* __restrict__ abt,
    const float* __restrict__ dgm, const float* __restrict__ dbt,
    float* __restrict__ out)
{
  const int bb   = (int)blockIdx.x >> 3;   // batch
  const int cc   = (int)blockIdx.x & 7;    // column chunk (128 cols)
  const int tid  = (int)threadIdx.x;
  const int w    = tid >> 6;               // wave == feature
  const int lane = tid & 63;
  const int fu   = __builtin_amdgcn_readfirstlane(w);
  const float* __restrict__ wpk = wpack + fu * 160;   // [ci][16], wave-uniform

  const int c0    = 2 * lane;              // chunk-local col
  const int gc0   = cc * 128 + c0;         // global col
  const int cellbase = bb * 8192 + w * 1024 + gc0;
  const int rep16 = (int)blockIdx.x & 15;  // stat replica class

  const float ggamma = ggm[fu], gbeta = gbt[fu];
  const float ugamma = ugm[fu], ubeta = ubt[fu];
  const float agamma = agm[fu], abeta = abt[fu];
  const float dgamma = dgm[fu], dbeta = dbt[fu];

  __shared__ float hl[8][136];   // row: [2 zero][2 haloL][128 own][2 haloR][2 zero]

  // ---- own-col states (2 cells) + halo states (lanes 0-3, 1 cell each) ----
  float nst[2], dst[2], amst[2], hv[2];
  float hn = 0.f, hd = 0.f, ham = -1e38f;
  const int  hloc   = (lane < 2) ? (lane - 2) : (128 + (lane - 2)); // -2,-1,128,129
  const bool hvalid = (lane < 4) && ((lane < 2) ? (cc > 0) : (cc < 7));
  {
    const float2 n2 = *(const float2*)(n_in  + cellbase);
    const float2 d2 = *(const float2*)(d_in  + cellbase);
    const float2 a2 = *(const float2*)(am_in + cellbase);
    const float2 h2 = *(const float2*)(h_in  + cellbase);
    const float2 s2 = *(const float2*)(s_in  + cellbase);
    nst[0] = n2.x; nst[1] = n2.y;
    dst[0] = d2.x; dst[1] = d2.y;
    amst[0] = a2.x; amst[1] = a2.y;
    hv[0] = h2.x + fast_tanh(s2.x);
    hv[1] = h2.y + fast_tanh(s2.y);
    *(float2*)&hl[w][c0 + 4] = make_float2(hv[0], hv[1]);

    float hh0 = 0.f;
    if (hvalid) {
      const int gcell = bb * 8192 + w * 1024 + cc * 128 + hloc;
      hn  = n_in[gcell]; hd = d_in[gcell]; ham = am_in[gcell];
      hh0 = h_in[gcell] + fast_tanh(s_in[gcell]);
    }
    if (lane < 4) hl[w][hloc + 4] = hh0;
    if (lane >= 4 && lane < 8) {   // zero guard pads
      const int pidx = (lane == 4) ? 0 : (lane == 5) ? 1 : (lane == 6) ? 134 : 135;
      hl[w][pidx] = 0.f;
    }
  }

  // initial XR window (t = 0)
  float2 xa, xb, xc;
  {
    const float2* xr2 = (const float2*)(XR + (size_t)bb * PROW + 2 + gc0);
    xa = xr2[0]; xb = xr2[1]; xc = xr2[2];
  }
  __syncthreads();

  for (int t = 0; t < Tt; ++t) {
    const int p2 = t & 1;
    const int p3 = t % 3;

    // ---- prefetch XR window for t+1 FIRST (latency hides under conv) --------
    float2 nxa, nxb, nxc;
    {
      const int tn = (t + 1 < Tt) ? (t + 1) : t;
      const float2* xr2 = (const float2*)(XR + (size_t)(tn * Bb + bb) * PROW + 2 + gc0);
      nxa = xr2[0]; nxb = xr2[1]; nxc = xr2[2];
    }

    // ---- phase A: conv over own 2 cols --------------------------------------
    float accg[2] = {0.f, 0.f}, acca[2] = {0.f, 0.f};
    float accd[2] = {0.f, 0.f}, accu[2] = {0.f, 0.f};

#pragma unroll
    for (int r = 0; r < 8; ++r) {          // input channels 1..8 = h rows
      const float2 qa = *(const float2*)&hl[r][c0 + 2];
      const float2 qb = *(const float2*)&hl[r][c0 + 4];
      const float2 qc = *(const float2*)&hl[r][c0 + 6];
      const float w6[6] = {qa.x, qa.y, qb.x, qb.y, qc.x, qc.y};
      const float* wp = wpk + (r + 1) * 16;
#pragma unroll
      for (int kw = 0; kw < 5; ++kw) {
        const float wg = wp[kw], wa = wp[5 + kw], wd = wp[10 + kw];
#pragma unroll
        for (int j = 0; j < 2; ++j) {
          const float v = w6[j + kw];
          accg[j] = fmaf(v, wg, accg[j]);
          acca[j] = fmaf(v, wa, acca[j]);
          accd[j] = fmaf(v, wd, accd[j]);
        }
      }
    }
    {                                      // input channel 0 = xr (+ u conv)
      const float w6[6] = {xa.x, xa.y, xb.x, xb.y, xc.x, xc.y};
      const float* wp = wpk;
      const float* wu = wpk + 144;
#pragma unroll
      for (int kw = 0; kw < 5; ++kw) {
        const float wg = wp[kw], wa = wp[5 + kw], wd = wp[10 + kw], wv = wu[kw];
#pragma unroll
        for (int j = 0; j < 2; ++j) {
          const float v = w6[j + kw];
          accg[j] = fmaf(v, wg, accg[j]);
          acca[j] = fmaf(v, wa, acca[j]);
          accd[j] = fmaf(v, wd, accd[j]);
          accu[j] = fmaf(v, wv, accu[j]);
        }
      }
    }

    // ---- BN partials: butterfly(1,2,4) -> select -> butterfly(8,16,32) ------
    {
      float ps[8];
      ps[0] = accg[0] + accg[1]; ps[1] = fmaf(accg[0], accg[0], accg[1] * accg[1]);
      ps[2] = acca[0] + acca[1]; ps[3] = fmaf(acca[0], acca[0], acca[1] * acca[1]);
      ps[4] = accd[0] + accd[1]; ps[5] = fmaf(accd[0], accd[0], accd[1] * accd[1]);
      ps[6] = accu[0] + accu[1]; ps[7] = fmaf(accu[0], accu[0], accu[1] * accu[1]);
#pragma unroll
      for (int m = 1; m <= 4; m <<= 1)
#pragma unroll
        for (int k = 0; k < 8; ++k) ps[k] += __shfl_xor(ps[k], m);
      const int l3 = lane & 7;
      const float a0 = (l3 & 1) ? ps[1] : ps[0];
      const float a1 = (l3 & 1) ? ps[3] : ps[2];
      const float a2 = (l3 & 1) ? ps[5] : ps[4];
      const float a3 = (l3 & 1) ? ps[7] : ps[6];
      const float b0 = (l3 & 2) ? a1 : a0;
      const float b1 = (l3 & 2) ? a3 : a2;
      float v = (l3 & 4) ? b1 : b0;
#pragma unroll
      for (int m = 8; m <= 32; m <<= 1) v += __shfl_xor(v, m);
      if (lane < 8)
        __hip_atomic_fetch_add(acc3 + p3 * 32768 + rep16 * 2048 + (w * 8 + lane) * 32,
                               v, __ATOMIC_RELAXED, __HIP_MEMORY_SCOPE_AGENT);
    }

    // ---- export raw conv outputs at boundary cols (packed u64) --------------
    if (lane == 0 || lane == 63) {
      const int side = lane ? 1 : 0;
      unsigned long long* bs = (unsigned long long*)
          (slots2 + ((((size_t)p2 * 32 + bb) * 8 + cc) * 2 + side) * 64 + w * 8);
      __hip_atomic_store(bs + 0, pack2(accg[0], accg[1]), __ATOMIC_RELAXED, __HIP_MEMORY_SCOPE_AGENT);
      __hip_atomic_store(bs + 1, pack2(acca[0], acca[1]), __ATOMIC_RELAXED, __HIP_MEMORY_SCOPE_AGENT);
      __hip_atomic_store(bs + 2, pack2(accd[0], accd[1]), __ATOMIC_RELAXED, __HIP_MEMORY_SCOPE_AGENT);
      __hip_atomic_store(bs + 3, pack2(accu[0], accu[1]), __ATOMIC_RELAXED, __HIP_MEMORY_SCOPE_AGENT);
    }

    // ---- barrier: arrive at leaf (fan-in 16); wave 0 polls all 16 leaves ----
    asm volatile("s_waitcnt vmcnt(0)" ::: "memory");
    __syncthreads();
    if (w == 0) {
      if (lane == 0)
        __hip_atomic_fetch_add(cnt + ((unsigned)blockIdx.x >> 4) * 32, 1u,
                               __ATOMIC_RELAXED, __HIP_MEMORY_SCOPE_AGENT);
      const unsigned tgt = 16u * (unsigned)(t + 1);
      for (;;) {
        unsigned c = 0u;
        if (lane < 16)
          c = __hip_atomic_load(cnt + lane * 32, __ATOMIC_RELAXED, __HIP_MEMORY_SCOPE_AGENT);
        if (__all((lane < 16) ? (int)(c >= tgt) : 1)) break;
        __builtin_amdgcn_s_sleep(1);
      }
    }
    __syncthreads();

    // ---- readback: stats (lanes 0-7, 16 reps) + halo exports (lanes 0-3) ----
    float v = 0.f;
    if (lane < 8) {
      const float* ap = acc3 + p3 * 32768 + (w * 8 + lane) * 32;
#pragma unroll
      for (int r = 0; r < 16; ++r)
        v += __hip_atomic_load(ap + r * 2048, __ATOMIC_RELAXED, __HIP_MEMORY_SCOPE_AGENT);
    }
    float graw = 0.f, araw = 0.f, draw = 0.f, uraw = 0.f;
    if (hvalid) {
      const int ncc  = (lane < 2) ? (cc - 1) : (cc + 1);
      const int nsid = (lane < 2) ? 1 : 0;
      const float* nb =
          slots2 + ((((size_t)p2 * 32 + bb) * 8 + ncc) * 2 + nsid) * 64 + w * 8 + (lane & 1);
      graw = __hip_atomic_load(nb + 0, __ATOMIC_RELAXED, __HIP_MEMORY_SCOPE_AGENT);
      araw = __hip_atomic_load(nb + 2, __ATOMIC_RELAXED, __HIP_MEMORY_SCOPE_AGENT);
      draw = __hip_atomic_load(nb + 4, __ATOMIC_RELAXED, __HIP_MEMORY_SCOPE_AGENT);
      uraw = __hip_atomic_load(nb + 6, __ATOMIC_RELAXED, __HIP_MEMORY_SCOPE_AGENT);
    }
    // distributed zeroing of parity (t+2)%3: 4 lines per block (1024 total)
    if (tid >= 256 && tid < 260) {
      const int idx = ((int)blockIdx.x << 2) + (tid - 256);   // 0..1023
      __hip_atomic_store(acc3 + ((t + 2) % 3) * 32768 + (idx >> 6) * 2048 + (idx & 63) * 32,
                         0.f, __ATOMIC_RELAXED, __HIP_MEMORY_SCOPE_AGENT);
    }

    float st[8];
#pragma unroll
    for (int k = 0; k < 8; ++k) st[k] = __shfl(v, k);

    const float mg = st[0] * INV_N; const float vg = fmaf(-mg, mg, st[1] * INV_N);
    const float sg = ggamma * rsqrtf(vg + EPSf); const float og = fmaf(-mg, sg, gbeta);
    const float ma = st[2] * INV_N; const float va = fmaf(-ma, ma, st[3] * INV_N);
    const float sa = agamma * rsqrtf(va + EPSf); const float oa = fmaf(-ma, sa, abeta);
    const float md = st[4] * INV_N; const float vd = fmaf(-md, md, st[5] * INV_N);
    const float sd = dgamma * rsqrtf(vd + EPSf); const float od = fmaf(-md, sd, dbeta);
    const float mu = st[6] * INV_N; const float vu = fmaf(-mu, mu, st[7] * INV_N);
    const float su = ugamma * rsqrtf(vu + EPSf); const float ou = fmaf(-mu, su, ubeta);

    // ---- phase B: own cells -------------------------------------------------
#pragma unroll
    for (int j = 0; j < 2; ++j) {
      const float gb = fmaf(accg[j], sg, og);
      const float ab = fmaf(acca[j], sa, oa);
      const float db = fmaf(accd[j], sd, od);
      const float ub = fmaf(accu[j], su, ou);
      const float dec = 1.0f / (1.0f + __expf(-db));
      const float ed  = __expf(-dec);
      const float z   = ub * fast_tanh(gb);
      const float anew = fmaxf(amst[j] * ed, ab);
      const float e1 = __expf(amst[j] - anew);
      const float e2 = __expf(ab - anew);
      const float ede1 = ed * e1;
      nst[j]  = fmaf(nst[j], ede1, z * e2);
      dst[j]  = fmaf(dst[j], ede1, e2);
      amst[j] = anew;
      hv[j]   = fast_tanh(nst[j] / dst[j]);
    }
    *(float2*)&hl[w][c0 + 4] = make_float2(hv[0], hv[1]);

    // ---- phase B: replicated halo cells (lanes 0-3) -------------------------
    if (lane < 4) {
      float hres = 0.f;
      if (hvalid) {
        const float gb = fmaf(graw, sg, og);
        const float ab = fmaf(araw, sa, oa);
        const float db = fmaf(draw, sd, od);
        const float ub = fmaf(uraw, su, ou);
        const float dec = 1.0f / (1.0f + __expf(-db));
        const float ed  = __expf(-dec);
        const float z   = ub * fast_tanh(gb);
        const float anew = fmaxf(ham * ed, ab);
        const float e1 = __expf(ham - anew);
        const float e2 = __expf(ab - anew);
        const float ede1 = ed * e1;
        hn  = fmaf(hn, ede1, z * e2);
        hd  = fmaf(hd, ede1, e2);
        ham = anew;
        hres = fast_tanh(hn / hd);
      }
      hl[w][hloc + 4] = hres;
    }
    __syncthreads();

    xa = nxa; xb = nxb; xc = nxc;
  }

  // ---- final outputs --------------------------------------------------------
  {
    const float2 s2 = *(const float2*)(s_in + cellbase);
    *(float2*)(out + OUT_S  + cellbase) = s2;
    *(float2*)(out + OUT_N  + cellbase) = make_float2(nst[0], nst[1]);
    *(float2*)(out + OUT_D  + cellbase) = make_float2(dst[0], dst[1]);
    *(float2*)(out + OUT_H  + cellbase) = make_float2(hv[0], hv[1]);
    *(float2*)(out + OUT_AM + cellbase) = make_float2(amst[0], amst[1]);
  }
}

// ---------------------------------------------------------------------------
// out[b][o] = dot(h_flat[b], o_w[o]) + o_b[o].  Block = one o (1000 blocks);
// thread t covers cols [t*32, t*32+32); 32 per-b accumulators -> butterfly.
// ---------------------------------------------------------------------------
__global__ void __launch_bounds__(256) out_kernel(const float* __restrict__ outH,
                                                  const float* __restrict__ ow,
                                                  const float* __restrict__ ob,
                                                  float* __restrict__ out) {
  const int o   = blockIdx.x;
  const int tid = (int)threadIdx.x;
  const int wv  = tid >> 6;
  const int lane = tid & 63;

  float4 wr[8];
  {
    const float4* wq = (const float4*)(ow + (size_t)o * 8192 + tid * 32);
#pragma unroll
    for (int k = 0; k < 8; ++k) wr[k] = wq[k];
  }
  float acc[32];
#pragma unroll
  for (int b = 0; b < 32; ++b) {
    const float4* hq = (const float4*)(outH + (size_t)b * 8192 + tid * 32);
    float s0 = 0.f, s1 = 0.f;
#pragma unroll
    for (int k = 0; k < 8; k += 2) {
      const float4 h0 = hq[k], h1 = hq[k + 1];
      s0 = fmaf(h0.x, wr[k].x, s0);     s0 = fmaf(h0.y, wr[k].y, s0);
      s0 = fmaf(h0.z, wr[k].z, s0);     s0 = fmaf(h0.w, wr[k].w, s0);
      s1 = fmaf(h1.x, wr[k+1].x, s1);   s1 = fmaf(h1.y, wr[k+1].y, s1);
      s1 = fmaf(h1.z, wr[k+1].z, s1);   s1 = fmaf(h1.w, wr[k+1].w, s1);
    }
    acc[b] = s0 + s1;
  }
#pragma unroll
  for (int m = 1; m <= 32; m <<= 1)
#pragma unroll
    for (int b = 0; b < 32; ++b) acc[b] += __shfl_xor(acc[b], m);

  __shared__ float red[4][32];
  if (lane < 32) red[wv][lane] = acc[lane];
  __syncthreads();
  if (tid < 32)
    out[tid * 1000 + o] = red[0][tid] + red[1][tid] + red[2][tid] + red[3][tid] + ob[o];
}

// ---------------------------------------------------------------------------
extern "C" void kernel_launch(void* const* d_in, const int* in_sizes, int n_in,
                              void* d_out, int out_size, void* d_ws, size_t ws_size,
                              hipStream_t stream) {
  (void)in_sizes; (void)n_in; (void)out_size; (void)ws_size;
  const float* x   = (const float*)d_in[0];
  const float* s   = (const float*)d_in[1];
  const float* n_  = (const float*)d_in[2];
  const float* dd  = (const float*)d_in[3];
  const float* h   = (const float*)d_in[4];
  const float* am  = (const float*)d_in[5];
  const float* xrw = (const float*)d_in[6];
  const float* gw  = (const float*)d_in[7];
  const float* ggm = (const float*)d_in[9];
  const float* gbt = (const float*)d_in[10];
  const float* uw  = (const float*)d_in[11];
  const float* ugm = (const float*)d_in[13];
  const float* ubt = (const float*)d_in[14];
  const float* aw  = (const float*)d_in[15];
  const float* agm = (const float*)d_in[17];
  const float* abt = (const float*)d_in[18];
  const float* dw  = (const float*)d_in[19];
  const float* dgm = (const float*)d_in[21];
  const float* dbt = (const float*)d_in[22];
  const float* ow  = (const float*)d_in[23];
  const float* ob  = (const float*)d_in[24];
  float* out = (float*)d_out;
  float* ws  = (float*)d_ws;

  float* XR     = ws + XR_OFF;
  float* wT     = ws + WT_OFF;
  float* wpack  = ws + WPK_OFF;
  float* acc3   = ws + ACC_OFF;
  float* slots2 = ws + SL2_OFF;
  unsigned* cnt = (unsigned*)(ws + CNT_OFF);

  prep_kernel<<<dim3(512), dim3(256), 0, stream>>>(xrw, wT, gw, aw, dw, uw, wpack, acc3, cnt);
  xr_kernel<<<dim3(256), dim3(256), 0, stream>>>(x, wT, XR);

  void* args[] = { &XR, &wpack, &acc3, &slots2, &cnt, &s, &n_, &dd, &h, &am,
                   &ggm, &gbt, &ugm, &ubt, &agm, &abt, &dgm, &dbt, &out };
  hipError_t err = hipLaunchCooperativeKernel((void*)scan_kernel, dim3(NBLK), dim3(NTHR),
                                              args, 0, stream);
  if (err != hipSuccess) {
    scan_kernel<<<dim3(NBLK), dim3(NTHR), 0, stream>>>(XR, wpack, acc3, slots2, cnt,
                                                       s, n_, dd, h, am,
                                                       ggm, gbt, ugm, ubt, agm, abt,
                                                       dgm, dbt, out);
  }

  out_kernel<<<dim3(1000), dim3(256), 0, stream>>>(out + OUT_H, ow, ob, out);
}

// Round 6
// 1331.001 us; speedup vs baseline: 1.2199x; 1.2199x over previous
//
#include <hip/hip_runtime.h>

// ---------------------------------------------------------------------------
// RWA recurrent cell, MI355X — round 6.
// 256 blocks = 32 batches x 8 column-chunks, 512 threads (wave = feature).
// Sync rules (r3/r4/r5 lessons):
//   - arrive on lines nobody reads (leaf 16x16 -> root), poll ONE write-once
//     gen line (r3 design; polling RMW'd lines delays the RMWs).
//   - BN stats: 16 replicas (fan-in 16/line) -> short RMW queues.
//   - XR(t+1) prefetched at top of phase A; boundary exports issued before
//     the stat reduce so their RT overlaps the shuffle chain.
// ---------------------------------------------------------------------------

#define NBLK 256
#define NTHR 512

constexpr int Bb = 32, Tt = 128, NCc = 1024;
constexpr int PROW = 1032;       // padded XR row: [4 zeros][1024][4 zeros]
constexpr float EPSf  = 1e-5f;
constexpr float INV_N = 1.0f / 32768.0f;   // 1/(B*NC)

// workspace layout (floats)
constexpr size_t XR_OFF  = 0;
constexpr size_t XR_SZ   = (size_t)Tt * Bb * PROW;     // 4,227,072
constexpr size_t WT_OFF  = XR_OFF + XR_SZ;
constexpr size_t WT_SZ   = 131072;                     // [128][1024] W^T
constexpr size_t WPK_OFF = WT_OFF + WT_SZ;
constexpr size_t WPK_SZ  = 1280;                       // [8][10][16] packed conv w
constexpr size_t ACC_OFF = WPK_OFF + WPK_SZ;           // [3 par][16 rep][64][32]
constexpr size_t ACC_SZ  = 3 * 16 * 64 * 32;           // 98,304
constexpr size_t SL2_OFF = ACC_OFF + ACC_SZ;           // [2 par][32 bb][8 cc][2 side][64]
constexpr size_t SL2_SZ  = 2 * 32 * 8 * 2 * 64;        // 65,536
constexpr size_t CNT_OFF = SL2_OFF + SL2_SZ;           // leaf[16]/root/gen, 128B apart

// output offsets (floats): (outs, s, n, d, h, a_max)
constexpr int OUT_S  = 32000;
constexpr int OUT_N  = 294144;
constexpr int OUT_D  = 556288;
constexpr int OUT_H  = 818432;
constexpr int OUT_AM = 1080576;

__device__ __forceinline__ float fast_tanh(float x) {
  float e = __expf(2.0f * x);
  return 1.0f - 2.0f / (e + 1.0f);
}

__device__ __forceinline__ unsigned long long pack2(float a, float b) {
  return (unsigned long long)__float_as_uint(a) |
         ((unsigned long long)__float_as_uint(b) << 32);
}

// ---------------------------------------------------------------------------
__global__ void prep_kernel(const float* __restrict__ w, float* __restrict__ wT,
                            const float* __restrict__ gw, const float* __restrict__ aw,
                            const float* __restrict__ dw, const float* __restrict__ uw,
                            float* __restrict__ wpack, float* __restrict__ acc3,
                            unsigned* __restrict__ cnt) {
  const int g = blockIdx.x * 256 + threadIdx.x;
  if (g < 131072) {
    const int c = g >> 7, k = g & 127;
    wT[k * 1024 + c] = w[g];
  }
  if (g < 1280) {
    const int f = g / 160, r = g % 160, ci = r >> 4, k = r & 15;
    float v = 0.f;
    if (ci < 9) {
      if (k < 5)       v = gw[(f * 9 + ci) * 5 + k];
      else if (k < 10) v = aw[(f * 9 + ci) * 5 + (k - 5)];
      else if (k < 15) v = dw[(f * 9 + ci) * 5 + (k - 10)];
    } else {
      if (k < 5)       v = uw[f * 5 + k];
    }
    wpack[g] = v;
  }
  if (g < (int)ACC_SZ) acc3[g] = 0.f;
  if (g < 1024) cnt[g] = 0u;
}

// ---------------------------------------------------------------------------
__global__ void __launch_bounds__(256) xr_kernel(const float* __restrict__ x,
                                                 const float* __restrict__ wT,
                                                 float* __restrict__ XR) {
  const int tb0 = blockIdx.x * 16;
  const int c0  = threadIdx.x * 4;
  float4 acc[16];
#pragma unroll
  for (int j = 0; j < 16; ++j) acc[j] = make_float4(0.f, 0.f, 0.f, 0.f);
#pragma unroll 4
  for (int k = 0; k < 128; ++k) {
    const float4 wv = *(const float4*)(wT + (size_t)k * 1024 + c0);
#pragma unroll
    for (int j = 0; j < 16; ++j) {
      const int tb = tb0 + j;
      const float xs = x[(size_t)(tb & 31) * 16384 + (size_t)(tb >> 5) * 128 + k];
      acc[j].x = fmaf(xs, wv.x, acc[j].x);
      acc[j].y = fmaf(xs, wv.y, acc[j].y);
      acc[j].z = fmaf(xs, wv.z, acc[j].z);
      acc[j].w = fmaf(xs, wv.w, acc[j].w);
    }
  }
#pragma unroll
  for (int j = 0; j < 16; ++j) {
    float* row = XR + (size_t)(tb0 + j) * PROW;
    *(float4*)(row + 4 + c0) = acc[j];
    if (threadIdx.x == 0)   { row[0] = row[1] = row[2] = row[3] = 0.f; }
    if (threadIdx.x == 255) { row[1028] = row[1029] = row[1030] = row[1031] = 0.f; }
  }
}

// ---------------------------------------------------------------------------
// scan: block=(bb,cc); wave=feature f; lane owns cols {2l, 2l+1} of chunk.
// ---------------------------------------------------------------------------
__global__ void __launch_bounds__(NTHR) scan_kernel(
    const float* __restrict__ XR, const float* __restrict__ wpack,
    float* acc3, float* slots2, unsigned* cnt,
    const float* __restrict__ s_in, const float* __restrict__ n_in,
    const float* __restrict__ d_in, const float* __restrict__ h_in,
    const float* __restrict__ am_in,
    const float* __restrict__ ggm, const float* __restrict__ gbt,
    const float* __restrict__ ugm, const float* __restrict__ ubt,
    const float* __restrict__ agm, const float* __restrict__ abt,
    const float* __restrict__ dgm, const float* __restrict__ dbt,
    float* __restrict__ out)
{
  const int bb   = (int)blockIdx.x >> 3;   // batch
  const int cc   = (int)blockIdx.x & 7;    // column chunk (128 cols)
  const int tid  = (int)threadIdx.x;
  const int w    = tid >> 6;               // wave == feature
  const int lane = tid & 63;
  const int fu   = __builtin_amdgcn_readfirstlane(w);
  const float* __restrict__ wpk = wpack + fu * 160;   // [ci][16], wave-uniform

  const int c0    = 2 * lane;              // chunk-local col
  const int gc0   = cc * 128 + c0;         // global col
  const int cellbase = bb * 8192 + w * 1024 + gc0;
  const int rep16 = (int)blockIdx.x & 15;  // stat replica class

  const float ggamma = ggm[fu], gbeta = gbt[fu];
  const float ugamma = ugm[fu], ubeta = ubt[fu];
  const float agamma = agm[fu], abeta = abt[fu];
  const float dgamma = dgm[fu], dbeta = dbt[fu];

  __shared__ float hl[8][136];   // row: [2 zero][2 haloL][128 own][2 haloR][2 zero]

  // ---- own-col states (2 cells) + halo states (lanes 0-3, 1 cell each) ----
  float nst[2], dst[2], amst[2], hv[2];
  float hn = 0.f, hd = 0.f, ham = -1e38f;
  const int  hloc   = (lane < 2) ? (lane - 2) : (128 + (lane - 2)); // -2,-1,128,129
  const bool hvalid = (lane < 4) && ((lane < 2) ? (cc > 0) : (cc < 7));
  {
    const float2 n2 = *(const float2*)(n_in  + cellbase);
    const float2 d2 = *(const float2*)(d_in  + cellbase);
    const float2 a2 = *(const float2*)(am_in + cellbase);
    const float2 h2 = *(const float2*)(h_in  + cellbase);
    const float2 s2 = *(const float2*)(s_in  + cellbase);
    nst[0] = n2.x; nst[1] = n2.y;
    dst[0] = d2.x; dst[1] = d2.y;
    amst[0] = a2.x; amst[1] = a2.y;
    hv[0] = h2.x + fast_tanh(s2.x);
    hv[1] = h2.y + fast_tanh(s2.y);
    *(float2*)&hl[w][c0 + 4] = make_float2(hv[0], hv[1]);

    float hh0 = 0.f;
    if (hvalid) {
      const int gcell = bb * 8192 + w * 1024 + cc * 128 + hloc;
      hn  = n_in[gcell]; hd = d_in[gcell]; ham = am_in[gcell];
      hh0 = h_in[gcell] + fast_tanh(s_in[gcell]);
    }
    if (lane < 4) hl[w][hloc + 4] = hh0;
    if (lane >= 4 && lane < 8) {   // zero guard pads
      const int pidx = (lane == 4) ? 0 : (lane == 5) ? 1 : (lane == 6) ? 134 : 135;
      hl[w][pidx] = 0.f;
    }
  }

  // initial XR window (t = 0)
  float2 xa, xb, xc;
  {
    const float2* xr2 = (const float2*)(XR + (size_t)bb * PROW + 2 + gc0);
    xa = xr2[0]; xb = xr2[1]; xc = xr2[2];
  }
  __syncthreads();

  for (int t = 0; t < Tt; ++t) {
    const int p2 = t & 1;
    const int p3 = t % 3;

    // ---- prefetch XR window for t+1 FIRST (latency hides under conv) --------
    float2 nxa, nxb, nxc;
    {
      const int tn = (t + 1 < Tt) ? (t + 1) : t;
      const float2* xr2 = (const float2*)(XR + (size_t)(tn * Bb + bb) * PROW + 2 + gc0);
      nxa = xr2[0]; nxb = xr2[1]; nxc = xr2[2];
    }

    // ---- phase A: conv over own 2 cols --------------------------------------
    float accg[2] = {0.f, 0.f}, acca[2] = {0.f, 0.f};
    float accd[2] = {0.f, 0.f}, accu[2] = {0.f, 0.f};

#pragma unroll
    for (int r = 0; r < 8; ++r) {          // input channels 1..8 = h rows
      const float2 qa = *(const float2*)&hl[r][c0 + 2];
      const float2 qb = *(const float2*)&hl[r][c0 + 4];
      const float2 qc = *(const float2*)&hl[r][c0 + 6];
      const float w6[6] = {qa.x, qa.y, qb.x, qb.y, qc.x, qc.y};
      const float* wp = wpk + (r + 1) * 16;
#pragma unroll
      for (int kw = 0; kw < 5; ++kw) {
        const float wg = wp[kw], wa = wp[5 + kw], wd = wp[10 + kw];
#pragma unroll
        for (int j = 0; j < 2; ++j) {
          const float v = w6[j + kw];
          accg[j] = fmaf(v, wg, accg[j]);
          acca[j] = fmaf(v, wa, acca[j]);
          accd[j] = fmaf(v, wd, accd[j]);
        }
      }
    }
    {                                      // input channel 0 = xr (+ u conv)
      const float w6[6] = {xa.x, xa.y, xb.x, xb.y, xc.x, xc.y};
      const float* wp = wpk;
      const float* wu = wpk + 144;
#pragma unroll
      for (int kw = 0; kw < 5; ++kw) {
        const float wg = wp[kw], wa = wp[5 + kw], wd = wp[10 + kw], wv = wu[kw];
#pragma unroll
        for (int j = 0; j < 2; ++j) {
          const float v = w6[j + kw];
          accg[j] = fmaf(v, wg, accg[j]);
          acca[j] = fmaf(v, wa, acca[j]);
          accd[j] = fmaf(v, wd, accd[j]);
          accu[j] = fmaf(v, wv, accu[j]);
        }
      }
    }

    // ---- export raw conv outputs at boundary cols FIRST (overlap with reduce)
    if (lane == 0 || lane == 63) {
      const int side = lane ? 1 : 0;
      unsigned long long* bs = (unsigned long long*)
          (slots2 + ((((size_t)p2 * 32 + bb) * 8 + cc) * 2 + side) * 64 + w * 8);
      __hip_atomic_store(bs + 0, pack2(accg[0], accg[1]), __ATOMIC_RELAXED, __HIP_MEMORY_SCOPE_AGENT);
      __hip_atomic_store(bs + 1, pack2(acca[0], acca[1]), __ATOMIC_RELAXED, __HIP_MEMORY_SCOPE_AGENT);
      __hip_atomic_store(bs + 2, pack2(accd[0], accd[1]), __ATOMIC_RELAXED, __HIP_MEMORY_SCOPE_AGENT);
      __hip_atomic_store(bs + 3, pack2(accu[0], accu[1]), __ATOMIC_RELAXED, __HIP_MEMORY_SCOPE_AGENT);
    }

    // ---- BN partials: butterfly(1,2,4) -> select -> butterfly(8,16,32) ------
    {
      float ps[8];
      ps[0] = accg[0] + accg[1]; ps[1] = fmaf(accg[0], accg[0], accg[1] * accg[1]);
      ps[2] = acca[0] + acca[1]; ps[3] = fmaf(acca[0], acca[0], acca[1] * acca[1]);
      ps[4] = accd[0] + accd[1]; ps[5] = fmaf(accd[0], accd[0], accd[1] * accd[1]);
      ps[6] = accu[0] + accu[1]; ps[7] = fmaf(accu[0], accu[0], accu[1] * accu[1]);
#pragma unroll
      for (int m = 1; m <= 4; m <<= 1)
#pragma unroll
        for (int k = 0; k < 8; ++k) ps[k] += __shfl_xor(ps[k], m);
      const int l3 = lane & 7;
      const float a0 = (l3 & 1) ? ps[1] : ps[0];
      const float a1 = (l3 & 1) ? ps[3] : ps[2];
      const float a2 = (l3 & 1) ? ps[5] : ps[4];
      const float a3 = (l3 & 1) ? ps[7] : ps[6];
      const float b0 = (l3 & 2) ? a1 : a0;
      const float b1 = (l3 & 2) ? a3 : a2;
      float v = (l3 & 4) ? b1 : b0;
#pragma unroll
      for (int m = 8; m <= 32; m <<= 1) v += __shfl_xor(v, m);
      if (lane < 8)
        __hip_atomic_fetch_add(acc3 + p3 * 32768 + rep16 * 2048 + (w * 8 + lane) * 32,
                               v, __ATOMIC_RELAXED, __HIP_MEMORY_SCOPE_AGENT);
    }

    // ---- barrier (r3 design): leaf(16x16) -> root -> write-once gen; poll gen
    asm volatile("s_waitcnt vmcnt(0)" ::: "memory");
    __syncthreads();
    if (tid == 0) {
      unsigned* leaf = cnt + ((unsigned)blockIdx.x >> 4) * 32;
      unsigned* root = cnt + 16 * 32;
      unsigned* gen  = cnt + 17 * 32;
      const unsigned tgt = (unsigned)(t + 1);
      const unsigned old =
          __hip_atomic_fetch_add(leaf, 1u, __ATOMIC_RELAXED, __HIP_MEMORY_SCOPE_AGENT);
      if (old == 16u * tgt - 1u) {
        const unsigned old2 =
            __hip_atomic_fetch_add(root, 1u, __ATOMIC_RELAXED, __HIP_MEMORY_SCOPE_AGENT);
        if (old2 == 16u * tgt - 1u)
          __hip_atomic_store(gen, tgt, __ATOMIC_RELAXED, __HIP_MEMORY_SCOPE_AGENT);
      }
      while (__hip_atomic_load(gen, __ATOMIC_RELAXED, __HIP_MEMORY_SCOPE_AGENT) < tgt)
        __builtin_amdgcn_s_sleep(1);
    }
    __syncthreads();

    // ---- readback: stats (lanes 0-7, 16 reps) + halo exports (lanes 0-3) ----
    float v = 0.f;
    if (lane < 8) {
      const float* ap = acc3 + p3 * 32768 + (w * 8 + lane) * 32;
#pragma unroll
      for (int r = 0; r < 16; ++r)
        v += __hip_atomic_load(ap + r * 2048, __ATOMIC_RELAXED, __HIP_MEMORY_SCOPE_AGENT);
    }
    float graw = 0.f, araw = 0.f, draw = 0.f, uraw = 0.f;
    if (hvalid) {
      const int ncc  = (lane < 2) ? (cc - 1) : (cc + 1);
      const int nsid = (lane < 2) ? 1 : 0;
      const float* nb =
          slots2 + ((((size_t)p2 * 32 + bb) * 8 + ncc) * 2 + nsid) * 64 + w * 8 + (lane & 1);
      graw = __hip_atomic_load(nb + 0, __ATOMIC_RELAXED, __HIP_MEMORY_SCOPE_AGENT);
      araw = __hip_atomic_load(nb + 2, __ATOMIC_RELAXED, __HIP_MEMORY_SCOPE_AGENT);
      draw = __hip_atomic_load(nb + 4, __ATOMIC_RELAXED, __HIP_MEMORY_SCOPE_AGENT);
      uraw = __hip_atomic_load(nb + 6, __ATOMIC_RELAXED, __HIP_MEMORY_SCOPE_AGENT);
    }
    // distributed zeroing of parity (t+2)%3: 4 lines per block (1024 total)
    if (tid >= 256 && tid < 260) {
      const int idx = ((int)blockIdx.x << 2) + (tid - 256);   // 0..1023
      __hip_atomic_store(acc3 + ((t + 2) % 3) * 32768 + (idx >> 6) * 2048 + (idx & 63) * 32,
                         0.f, __ATOMIC_RELAXED, __HIP_MEMORY_SCOPE_AGENT);
    }

    float st[8];
#pragma unroll
    for (int k = 0; k < 8; ++k) st[k] = __shfl(v, k);

    const float mg = st[0] * INV_N; const float vg = fmaf(-mg, mg, st[1] * INV_N);
    const float sg = ggamma * rsqrtf(vg + EPSf); const float og = fmaf(-mg, sg, gbeta);
    const float ma = st[2] * INV_N; const float va = fmaf(-ma, ma, st[3] * INV_N);
    const float sa = agamma * rsqrtf(va + EPSf); const float oa = fmaf(-ma, sa, abeta);
    const float md = st[4] * INV_N; const float vd = fmaf(-md, md, st[5] * INV_N);
    const float sd = dgamma * rsqrtf(vd + EPSf); const float od = fmaf(-md, sd, dbeta);
    const float mu = st[6] * INV_N; const float vu = fmaf(-mu, mu, st[7] * INV_N);
    const float su = ugamma * rsqrtf(vu + EPSf); const float ou = fmaf(-mu, su, ubeta);

    // ---- phase B: own cells -------------------------------------------------
#pragma unroll
    for (int j = 0; j < 2; ++j) {
      const float gb = fmaf(accg[j], sg, og);
      const float ab = fmaf(acca[j], sa, oa);
      const float db = fmaf(accd[j], sd, od);
      const float ub = fmaf(accu[j], su, ou);
      const float dec = 1.0f / (1.0f + __expf(-db));
      const float ed  = __expf(-dec);
      const float z   = ub * fast_tanh(gb);
      const float anew = fmaxf(amst[j] * ed, ab);
      const float e1 = __expf(amst[j] - anew);
      const float e2 = __expf(ab - anew);
      const float ede1 = ed * e1;
      nst[j]  = fmaf(nst[j], ede1, z * e2);
      dst[j]  = fmaf(dst[j], ede1, e2);
      amst[j] = anew;
      hv[j]   = fast_tanh(nst[j] / dst[j]);
    }
    *(float2*)&hl[w][c0 + 4] = make_float2(hv[0], hv[1]);

    // ---- phase B: replicated halo cells (lanes 0-3) -------------------------
    if (lane < 4) {
      float hres = 0.f;
      if (hvalid) {
        const float gb = fmaf(graw, sg, og);
        const float ab = fmaf(araw, sa, oa);
        const float db = fmaf(draw, sd, od);
        const float ub = fmaf(uraw, su, ou);
        const float dec = 1.0f / (1.0f + __expf(-db));
        const float ed  = __expf(-dec);
        const float z   = ub * fast_tanh(gb);
        const float anew = fmaxf(ham * ed, ab);
        const float e1 = __expf(ham - anew);
        const float e2 = __expf(ab - anew);
        const float ede1 = ed * e1;
        hn  = fmaf(hn, ede1, z * e2);
        hd  = fmaf(hd, ede1, e2);
        ham = anew;
        hres = fast_tanh(hn / hd);
      }
      hl[w][hloc + 4] = hres;
    }
    __syncthreads();

    xa = nxa; xb = nxb; xc = nxc;
  }

  // ---- final outputs --------------------------------------------------------
  {
    const float2 s2 = *(const float2*)(s_in + cellbase);
    *(float2*)(out + OUT_S  + cellbase) = s2;
    *(float2*)(out + OUT_N  + cellbase) = make_float2(nst[0], nst[1]);
    *(float2*)(out + OUT_D  + cellbase) = make_float2(dst[0], dst[1]);
    *(float2*)(out + OUT_H  + cellbase) = make_float2(hv[0], hv[1]);
    *(float2*)(out + OUT_AM + cellbase) = make_float2(amst[0], amst[1]);
  }
}

// ---------------------------------------------------------------------------
// out[b][o] = dot(h_flat[b], o_w[o]) + o_b[o].  Block = one o (1000 blocks);
// thread t covers cols [t*32, t*32+32); 32 per-b accumulators -> butterfly.
// ---------------------------------------------------------------------------
__global__ void __launch_bounds__(256) out_kernel(const float* __restrict__ outH,
                                                  const float* __restrict__ ow,
                                                  const float* __restrict__ ob,
                                                  float* __restrict__ out) {
  const int o   = blockIdx.x;
  const int tid = (int)threadIdx.x;
  const int wv  = tid >> 6;
  const int lane = tid & 63;

  float4 wr[8];
  {
    const float4* wq = (const float4*)(ow + (size_t)o * 8192 + tid * 32);
#pragma unroll
    for (int k = 0; k < 8; ++k) wr[k] = wq[k];
  }
  float acc[32];
#pragma unroll
  for (int b = 0; b < 32; ++b) {
    const float4* hq = (const float4*)(outH + (size_t)b * 8192 + tid * 32);
    float s0 = 0.f, s1 = 0.f;
#pragma unroll
    for (int k = 0; k < 8; k += 2) {
      const float4 h0 = hq[k], h1 = hq[k + 1];
      s0 = fmaf(h0.x, wr[k].x, s0);     s0 = fmaf(h0.y, wr[k].y, s0);
      s0 = fmaf(h0.z, wr[k].z, s0);     s0 = fmaf(h0.w, wr[k].w, s0);
      s1 = fmaf(h1.x, wr[k+1].x, s1);   s1 = fmaf(h1.y, wr[k+1].y, s1);
      s1 = fmaf(h1.z, wr[k+1].z, s1);   s1 = fmaf(h1.w, wr[k+1].w, s1);
    }
    acc[b] = s0 + s1;
  }
#pragma unroll
  for (int m = 1; m <= 32; m <<= 1)
#pragma unroll
    for (int b = 0; b < 32; ++b) acc[b] += __shfl_xor(acc[b], m);

  __shared__ float red[4][32];
  if (lane < 32) red[wv][lane] = acc[lane];
  __syncthreads();
  if (tid < 32)
    out[tid * 1000 + o] = red[0][tid] + red[1][tid] + red[2][tid] + red[3][tid] + ob[o];
}

// ---------------------------------------------------------------------------
extern "C" void kernel_launch(void* const* d_in, const int* in_sizes, int n_in,
                              void* d_out, int out_size, void* d_ws, size_t ws_size,
                              hipStream_t stream) {
  (void)in_sizes; (void)n_in; (void)out_size; (void)ws_size;
  const float* x   = (const float*)d_in[0];
  const float* s   = (const float*)d_in[1];
  const float* n_  = (const float*)d_in[2];
  const float* dd  = (const float*)d_in[3];
  const float* h   = (const float*)d_in[4];
  const float* am  = (const float*)d_in[5];
  const float* xrw = (const float*)d_in[6];
  const float* gw  = (const float*)d_in[7];
  const float* ggm = (const float*)d_in[9];
  const float* gbt = (const float*)d_in[10];
  const float* uw  = (const float*)d_in[11];
  const float* ugm = (const float*)d_in[13];
  const float* ubt = (const float*)d_in[14];
  const float* aw  = (const float*)d_in[15];
  const float* agm = (const float*)d_in[17];
  const float* abt = (const float*)d_in[18];
  const float* dw  = (const float*)d_in[19];
  const float* dgm = (const float*)d_in[21];
  const float* dbt = (const float*)d_in[22];
  const float* ow  = (const float*)d_in[23];
  const float* ob  = (const float*)d_in[24];
  float* out = (float*)d_out;
  float* ws  = (float*)d_ws;

  float* XR     = ws + XR_OFF;
  float* wT     = ws + WT_OFF;
  float* wpack  = ws + WPK_OFF;
  float* acc3   = ws + ACC_OFF;
  float* slots2 = ws + SL2_OFF;
  unsigned* cnt = (unsigned*)(ws + CNT_OFF);

  prep_kernel<<<dim3(512), dim3(256), 0, stream>>>(xrw, wT, gw, aw, dw, uw, wpack, acc3, cnt);
  xr_kernel<<<dim3(256), dim3(256), 0, stream>>>(x, wT, XR);

  void* args[] = { &XR, &wpack, &acc3, &slots2, &cnt, &s, &n_, &dd, &h, &am,
                   &ggm, &gbt, &ugm, &ubt, &agm, &abt, &dgm, &dbt, &out };
  hipError_t err = hipLaunchCooperativeKernel((void*)scan_kernel, dim3(NBLK), dim3(NTHR),
                                              args, 0, stream);
  if (err != hipSuccess) {
    scan_kernel<<<dim3(NBLK), dim3(NTHR), 0, stream>>>(XR, wpack, acc3, slots2, cnt,
                                                       s, n_, dd, h, am,
                                                       ggm, gbt, ugm, ubt, agm, abt,
                                                       dgm, dbt, out);
  }

  out_kernel<<<dim3(1000), dim3(256), 0, stream>>>(out + OUT_H, ow, ob, out);
}

// Round 8
// 1296.719 us; speedup vs baseline: 1.2522x; 1.0264x over previous
//
#include <hip/hip_runtime.h>

// ---------------------------------------------------------------------------
// RWA recurrent cell, MI355X — round 7 (resubmit; prior bench hit GPU
// acquisition timeout, kernel never ran).
// 256 compute blocks (32 batches x 8 column-chunks) + 1 dedicated reducer
// block. Per step:
//   compute: conv -> wave reduce -> stat atomicAdd (16 reps) + halo export
//            -> drain -> leaf arrive (16 lines, fan-in 16)
//            -> poll packed stats (u64 = tag|value; poll IS the readback)
//            -> BN + state update (+ replicated halo cells).
//   reducer: poll 16 leaves -> read 16 replicas -> write packed stats x4.
// Sync rules (r3-r6): arrive on lines only the reducer reads; compute blocks
// poll only write-once lines; per-line RMW fan-in <= 16.
// ---------------------------------------------------------------------------

#define NBLK 256
#define NTHR 512

constexpr int Bb = 32, Tt = 128, NCc = 1024;
constexpr int PROW = 1032;       // padded XR row: [4 zeros][1024][4 zeros]
constexpr float EPSf  = 1e-5f;
constexpr float INV_N = 1.0f / 32768.0f;   // 1/(B*NC)

// workspace layout (floats)
constexpr size_t XR_OFF  = 0;
constexpr size_t XR_SZ   = (size_t)Tt * Bb * PROW;     // 4,227,072
constexpr size_t WT_OFF  = XR_OFF + XR_SZ;
constexpr size_t WT_SZ   = 131072;                     // [128][1024] W^T
constexpr size_t WPK_OFF = WT_OFF + WT_SZ;
constexpr size_t WPK_SZ  = 1280;                       // [8][10][16] packed conv w
constexpr size_t ACC_OFF = WPK_OFF + WPK_SZ;           // [3 par][16 rep][64][32]
constexpr size_t ACC_SZ  = 3 * 16 * 64 * 32;           // 98,304
constexpr size_t SL2_OFF = ACC_OFF + ACC_SZ;           // [2 par][32 bb][8 cc][2 side][64]
constexpr size_t SL2_SZ  = 2 * 32 * 8 * 2 * 64;        // 65,536
constexpr size_t CNT_OFF = SL2_OFF + SL2_SZ;           // 16 leaves (128B apart) then
constexpr size_t STT_OFF = CNT_OFF + 512;              // packed stats [4 copies][64] u64

// output offsets (floats): (outs, s, n, d, h, a_max)
constexpr int OUT_S  = 32000;
constexpr int OUT_N  = 294144;
constexpr int OUT_D  = 556288;
constexpr int OUT_H  = 818432;
constexpr int OUT_AM = 1080576;

__device__ __forceinline__ float fast_tanh(float x) {
  float e = __expf(2.0f * x);
  return 1.0f - 2.0f / (e + 1.0f);
}

__device__ __forceinline__ unsigned long long pack2(float a, float b) {
  return (unsigned long long)__float_as_uint(a) |
         ((unsigned long long)__float_as_uint(b) << 32);
}

// ---------------------------------------------------------------------------
__global__ void prep_kernel(const float* __restrict__ w, float* __restrict__ wT,
                            const float* __restrict__ gw, const float* __restrict__ aw,
                            const float* __restrict__ dw, const float* __restrict__ uw,
                            float* __restrict__ wpack, float* __restrict__ acc3,
                            unsigned* __restrict__ cnt) {
  const int g = blockIdx.x * 256 + threadIdx.x;
  if (g < 131072) {
    const int c = g >> 7, k = g & 127;
    wT[k * 1024 + c] = w[g];
  }
  if (g < 1280) {
    const int f = g / 160, r = g % 160, ci = r >> 4, k = r & 15;
    float v = 0.f;
    if (ci < 9) {
      if (k < 5)       v = gw[(f * 9 + ci) * 5 + k];
      else if (k < 10) v = aw[(f * 9 + ci) * 5 + (k - 5)];
      else if (k < 15) v = dw[(f * 9 + ci) * 5 + (k - 10)];
    } else {
      if (k < 5)       v = uw[f * 5 + k];
    }
    wpack[g] = v;
  }
  if (g < (int)ACC_SZ) acc3[g] = 0.f;
  if (g < 2048) cnt[g] = 0u;     // leaves + packed-stat area
}

// ---------------------------------------------------------------------------
__global__ void __launch_bounds__(256) xr_kernel(const float* __restrict__ x,
                                                 const float* __restrict__ wT,
                                                 float* __restrict__ XR) {
  const int tb0 = blockIdx.x * 16;
  const int c0  = threadIdx.x * 4;
  float4 acc[16];
#pragma unroll
  for (int j = 0; j < 16; ++j) acc[j] = make_float4(0.f, 0.f, 0.f, 0.f);
#pragma unroll 4
  for (int k = 0; k < 128; ++k) {
    const float4 wv = *(const float4*)(wT + (size_t)k * 1024 + c0);
#pragma unroll
    for (int j = 0; j < 16; ++j) {
      const int tb = tb0 + j;
      const float xs = x[(size_t)(tb & 31) * 16384 + (size_t)(tb >> 5) * 128 + k];
      acc[j].x = fmaf(xs, wv.x, acc[j].x);
      acc[j].y = fmaf(xs, wv.y, acc[j].y);
      acc[j].z = fmaf(xs, wv.z, acc[j].z);
      acc[j].w = fmaf(xs, wv.w, acc[j].w);
    }
  }
#pragma unroll
  for (int j = 0; j < 16; ++j) {
    float* row = XR + (size_t)(tb0 + j) * PROW;
    *(float4*)(row + 4 + c0) = acc[j];
    if (threadIdx.x == 0)   { row[0] = row[1] = row[2] = row[3] = 0.f; }
    if (threadIdx.x == 255) { row[1028] = row[1029] = row[1030] = row[1031] = 0.f; }
  }
}

// ---------------------------------------------------------------------------
// scan: block=(bb,cc); wave=feature f; lane owns cols {2l, 2l+1} of chunk.
// block NBLK is the dedicated stat reducer.
// ---------------------------------------------------------------------------
__global__ void __launch_bounds__(NTHR) scan_kernel(
    const float* __restrict__ XR, const float* __restrict__ wpack,
    float* acc3, float* slots2, unsigned* cnt, unsigned long long* stt,
    const float* __restrict__ s_in, const float* __restrict__ n_in,
    const float* __restrict__ d_in, const float* __restrict__ h_in,
    const float* __restrict__ am_in,
    const float* __restrict__ ggm, const float* __restrict__ gbt,
    const float* __restrict__ ugm, const float* __restrict__ ubt,
    const float* __restrict__ agm, const float* __restrict__ abt,
    const float* __restrict__ dgm, const float* __restrict__ dbt,
    float* __restrict__ out)
{
  const int tid  = (int)threadIdx.x;
  const int w    = tid >> 6;               // wave == feature
  const int lane = tid & 63;

  // ======================= dedicated reducer block ==========================
  if ((int)blockIdx.x == NBLK) {
    if (w == 0) {
      for (int t = 0; t < Tt; ++t) {
        const int p3 = t % 3;
        const unsigned tgt = 16u * (unsigned)(t + 1);
        for (;;) {
          unsigned c = 0u;
          if (lane < 16)
            c = __hip_atomic_load(cnt + lane * 32, __ATOMIC_RELAXED, __HIP_MEMORY_SCOPE_AGENT);
          if (__all((lane < 16) ? (int)(c >= tgt) : 1)) break;
          __builtin_amdgcn_s_sleep(1);
        }
        // read 16 replicas of this lane's stat line and sum
        float s = 0.f;
        const float* ap = acc3 + p3 * 32768 + lane * 32;
#pragma unroll
        for (int r = 0; r < 16; ++r)
          s += __hip_atomic_load(ap + r * 2048, __ATOMIC_RELAXED, __HIP_MEMORY_SCOPE_AGENT);
        // publish packed (tag|value), 4 copies
        const unsigned long long pv =
            ((unsigned long long)(unsigned)(t + 1) << 32) |
            (unsigned long long)__float_as_uint(s);
#pragma unroll
        for (int cp = 0; cp < 4; ++cp)
          __hip_atomic_store(stt + cp * 64 + lane, pv, __ATOMIC_RELAXED, __HIP_MEMORY_SCOPE_AGENT);
      }
    }
    return;
  }
  // ==========================================================================

  const int bb   = (int)blockIdx.x >> 3;   // batch
  const int cc   = (int)blockIdx.x & 7;    // column chunk (128 cols)
  const int fu   = __builtin_amdgcn_readfirstlane(w);
  const float* __restrict__ wpk = wpack + fu * 160;   // [ci][16], wave-uniform

  const int c0    = 2 * lane;              // chunk-local col
  const int gc0   = cc * 128 + c0;         // global col
  const int cellbase = bb * 8192 + w * 1024 + gc0;
  const int rep16 = (int)blockIdx.x >> 4;  // stat replica class == leaf group
  const int scp   = (int)blockIdx.x & 3;   // stat copy to poll

  const float ggamma = ggm[fu], gbeta = gbt[fu];
  const float ugamma = ugm[fu], ubeta = ubt[fu];
  const float agamma = agm[fu], abeta = abt[fu];
  const float dgamma = dgm[fu], dbeta = dbt[fu];

  __shared__ float hl[8][136];   // row: [2 zero][2 haloL][128 own][2 haloR][2 zero]

  // ---- own-col states (2 cells) + halo states (lanes 0-3, 1 cell each) ----
  float nst[2], dst[2], amst[2], hv[2];
  float hn = 0.f, hd = 0.f, ham = -1e38f;
  const int  hloc   = (lane < 2) ? (lane - 2) : (128 + (lane - 2)); // -2,-1,128,129
  const bool hvalid = (lane < 4) && ((lane < 2) ? (cc > 0) : (cc < 7));
  {
    const float2 n2 = *(const float2*)(n_in  + cellbase);
    const float2 d2 = *(const float2*)(d_in  + cellbase);
    const float2 a2 = *(const float2*)(am_in + cellbase);
    const float2 h2 = *(const float2*)(h_in  + cellbase);
    const float2 s2 = *(const float2*)(s_in  + cellbase);
    nst[0] = n2.x; nst[1] = n2.y;
    dst[0] = d2.x; dst[1] = d2.y;
    amst[0] = a2.x; amst[1] = a2.y;
    hv[0] = h2.x + fast_tanh(s2.x);
    hv[1] = h2.y + fast_tanh(s2.y);
    *(float2*)&hl[w][c0 + 4] = make_float2(hv[0], hv[1]);

    float hh0 = 0.f;
    if (hvalid) {
      const int gcell = bb * 8192 + w * 1024 + cc * 128 + hloc;
      hn  = n_in[gcell]; hd = d_in[gcell]; ham = am_in[gcell];
      hh0 = h_in[gcell] + fast_tanh(s_in[gcell]);
    }
    if (lane < 4) hl[w][hloc + 4] = hh0;
    if (lane >= 4 && lane < 8) {   // zero guard pads
      const int pidx = (lane == 4) ? 0 : (lane == 5) ? 1 : (lane == 6) ? 134 : 135;
      hl[w][pidx] = 0.f;
    }
  }

  // initial XR window (t = 0)
  float2 xa, xb, xc;
  {
    const float2* xr2 = (const float2*)(XR + (size_t)bb * PROW + 2 + gc0);
    xa = xr2[0]; xb = xr2[1]; xc = xr2[2];
  }
  __syncthreads();

  for (int t = 0; t < Tt; ++t) {
    const int p2 = t & 1;
    const int p3 = t % 3;

    // ---- prefetch XR window for t+1 FIRST (latency hides under conv) --------
    float2 nxa, nxb, nxc;
    {
      const int tn = (t + 1 < Tt) ? (t + 1) : t;
      const float2* xr2 = (const float2*)(XR + (size_t)(tn * Bb + bb) * PROW + 2 + gc0);
      nxa = xr2[0]; nxb = xr2[1]; nxc = xr2[2];
    }

    // ---- phase A: conv over own 2 cols --------------------------------------
    float accg[2] = {0.f, 0.f}, acca[2] = {0.f, 0.f};
    float accd[2] = {0.f, 0.f}, accu[2] = {0.f, 0.f};

#pragma unroll
    for (int r = 0; r < 8; ++r) {          // input channels 1..8 = h rows
      const float2 qa = *(const float2*)&hl[r][c0 + 2];
      const float2 qb = *(const float2*)&hl[r][c0 + 4];
      const float2 qc = *(const float2*)&hl[r][c0 + 6];
      const float w6[6] = {qa.x, qa.y, qb.x, qb.y, qc.x, qc.y};
      const float* wp = wpk + (r + 1) * 16;
#pragma unroll
      for (int kw = 0; kw < 5; ++kw) {
        const float wg = wp[kw], wa = wp[5 + kw], wd = wp[10 + kw];
#pragma unroll
        for (int j = 0; j < 2; ++j) {
          const float v = w6[j + kw];
          accg[j] = fmaf(v, wg, accg[j]);
          acca[j] = fmaf(v, wa, acca[j]);
          accd[j] = fmaf(v, wd, accd[j]);
        }
      }
    }
    {                                      // input channel 0 = xr (+ u conv)
      const float w6[6] = {xa.x, xa.y, xb.x, xb.y, xc.x, xc.y};
      const float* wp = wpk;
      const float* wu = wpk + 144;
#pragma unroll
      for (int kw = 0; kw < 5; ++kw) {
        const float wg = wp[kw], wa = wp[5 + kw], wd = wp[10 + kw], wv = wu[kw];
#pragma unroll
        for (int j = 0; j < 2; ++j) {
          const float v = w6[j + kw];
          accg[j] = fmaf(v, wg, accg[j]);
          acca[j] = fmaf(v, wa, acca[j]);
          accd[j] = fmaf(v, wd, accd[j]);
          accu[j] = fmaf(v, wv, accu[j]);
        }
      }
    }

    // ---- export raw conv outputs at boundary cols FIRST (overlap with reduce)
    if (lane == 0 || lane == 63) {
      const int side = lane ? 1 : 0;
      unsigned long long* bs = (unsigned long long*)
          (slots2 + ((((size_t)p2 * 32 + bb) * 8 + cc) * 2 + side) * 64 + w * 8);
      __hip_atomic_store(bs + 0, pack2(accg[0], accg[1]), __ATOMIC_RELAXED, __HIP_MEMORY_SCOPE_AGENT);
      __hip_atomic_store(bs + 1, pack2(acca[0], acca[1]), __ATOMIC_RELAXED, __HIP_MEMORY_SCOPE_AGENT);
      __hip_atomic_store(bs + 2, pack2(accd[0], accd[1]), __ATOMIC_RELAXED, __HIP_MEMORY_SCOPE_AGENT);
      __hip_atomic_store(bs + 3, pack2(accu[0], accu[1]), __ATOMIC_RELAXED, __HIP_MEMORY_SCOPE_AGENT);
    }

    // ---- BN partials: butterfly(1,2,4) -> select -> butterfly(8,16,32) ------
    {
      float ps[8];
      ps[0] = accg[0] + accg[1]; ps[1] = fmaf(accg[0], accg[0], accg[1] * accg[1]);
      ps[2] = acca[0] + acca[1]; ps[3] = fmaf(acca[0], acca[0], acca[1] * acca[1]);
      ps[4] = accd[0] + accd[1]; ps[5] = fmaf(accd[0], accd[0], accd[1] * accd[1]);
      ps[6] = accu[0] + accu[1]; ps[7] = fmaf(accu[0], accu[0], accu[1] * accu[1]);
#pragma unroll
      for (int m = 1; m <= 4; m <<= 1)
#pragma unroll
        for (int k = 0; k < 8; ++k) ps[k] += __shfl_xor(ps[k], m);
      const int l3 = lane & 7;
      const float a0 = (l3 & 1) ? ps[1] : ps[0];
      const float a1 = (l3 & 1) ? ps[3] : ps[2];
      const float a2 = (l3 & 1) ? ps[5] : ps[4];
      const float a3 = (l3 & 1) ? ps[7] : ps[6];
      const float b0 = (l3 & 2) ? a1 : a0;
      const float b1 = (l3 & 2) ? a3 : a2;
      float v = (l3 & 4) ? b1 : b0;
#pragma unroll
      for (int m = 8; m <= 32; m <<= 1) v += __shfl_xor(v, m);
      if (lane < 8)
        __hip_atomic_fetch_add(acc3 + p3 * 32768 + rep16 * 2048 + (w * 8 + lane) * 32,
                               v, __ATOMIC_RELAXED, __HIP_MEMORY_SCOPE_AGENT);
    }

    // ---- arrive: drain, then leaf add (reducer-only reads leaves) -----------
    asm volatile("s_waitcnt vmcnt(0)" ::: "memory");
    __syncthreads();
    if (tid == 0)
      __hip_atomic_fetch_add(cnt + ((unsigned)blockIdx.x >> 4) * 32, 1u,
                             __ATOMIC_RELAXED, __HIP_MEMORY_SCOPE_AGENT);

    // ---- poll packed stats: the successful poll IS the readback -------------
    float sv = 0.f;
    {
      const unsigned long long* sp = stt + scp * 64 + w * 8;
      const unsigned tagv = (unsigned)(t + 1);
      unsigned long long pv = 0ull;
      for (;;) {
        if (lane < 8)
          pv = __hip_atomic_load(sp + lane, __ATOMIC_RELAXED, __HIP_MEMORY_SCOPE_AGENT);
        if (__all((lane < 8) ? (int)((unsigned)(pv >> 32) == tagv) : 1)) break;
        __builtin_amdgcn_s_sleep(1);
      }
      sv = __uint_as_float((unsigned)pv);
    }

    // ---- halo-export readback (overlaps phase-B own-cell compute) -----------
    float graw = 0.f, araw = 0.f, draw = 0.f, uraw = 0.f;
    if (hvalid) {
      const int ncc  = (lane < 2) ? (cc - 1) : (cc + 1);
      const int nsid = (lane < 2) ? 1 : 0;
      const float* nb =
          slots2 + ((((size_t)p2 * 32 + bb) * 8 + ncc) * 2 + nsid) * 64 + w * 8 + (lane & 1);
      graw = __hip_atomic_load(nb + 0, __ATOMIC_RELAXED, __HIP_MEMORY_SCOPE_AGENT);
      araw = __hip_atomic_load(nb + 2, __ATOMIC_RELAXED, __HIP_MEMORY_SCOPE_AGENT);
      draw = __hip_atomic_load(nb + 4, __ATOMIC_RELAXED, __HIP_MEMORY_SCOPE_AGENT);
      uraw = __hip_atomic_load(nb + 6, __ATOMIC_RELAXED, __HIP_MEMORY_SCOPE_AGENT);
    }
    // distributed zeroing of parity (t+2)%3: 4 lines per block (1024 total)
    if (tid >= 256 && tid < 260) {
      const int idx = ((int)blockIdx.x << 2) + (tid - 256);   // 0..1023
      __hip_atomic_store(acc3 + ((t + 2) % 3) * 32768 + (idx >> 6) * 2048 + (idx & 63) * 32,
                         0.f, __ATOMIC_RELAXED, __HIP_MEMORY_SCOPE_AGENT);
    }

    float st[8];
#pragma unroll
    for (int k = 0; k < 8; ++k) st[k] = __shfl(sv, k);

    const float mg = st[0] * INV_N; const float vg = fmaf(-mg, mg, st[1] * INV_N);
    const float sg = ggamma * rsqrtf(vg + EPSf); const float og = fmaf(-mg, sg, gbeta);
    const float ma = st[2] * INV_N; const float va = fmaf(-ma, ma, st[3] * INV_N);
    const float sa = agamma * rsqrtf(va + EPSf); const float oa = fmaf(-ma, sa, abeta);
    const float md = st[4] * INV_N; const float vd = fmaf(-md, md, st[5] * INV_N);
    const float sd = dgamma * rsqrtf(vd + EPSf); const float od = fmaf(-md, sd, dbeta);
    const float mu = st[6] * INV_N; const float vu = fmaf(-mu, mu, st[7] * INV_N);
    const float su = ugamma * rsqrtf(vu + EPSf); const float ou = fmaf(-mu, su, ubeta);

    // ---- phase B: own cells -------------------------------------------------
#pragma unroll
    for (int j = 0; j < 2; ++j) {
      const float gb = fmaf(accg[j], sg, og);
      const float ab = fmaf(acca[j], sa, oa);
      const float db = fmaf(accd[j], sd, od);
      const float ub = fmaf(accu[j], su, ou);
      const float dec = 1.0f / (1.0f + __expf(-db));
      const float ed  = __expf(-dec);
      const float z   = ub * fast_tanh(gb);
      const float anew = fmaxf(amst[j] * ed, ab);
      const float e1 = __expf(amst[j] - anew);
      const float e2 = __expf(ab - anew);
      const float ede1 = ed * e1;
      nst[j]  = fmaf(nst[j], ede1, z * e2);
      dst[j]  = fmaf(dst[j], ede1, e2);
      amst[j] = anew;
      hv[j]   = fast_tanh(nst[j] / dst[j]);
    }
    *(float2*)&hl[w][c0 + 4] = make_float2(hv[0], hv[1]);

    // ---- phase B: replicated halo cells (lanes 0-3) -------------------------
    if (lane < 4) {
      float hres = 0.f;
      if (hvalid) {
        const float gb = fmaf(graw, sg, og);
        const float ab = fmaf(araw, sa, oa);
        const float db = fmaf(draw, sd, od);
        const float ub = fmaf(uraw, su, ou);
        const float dec = 1.0f / (1.0f + __expf(-db));
        const float ed  = __expf(-dec);
        const float z   = ub * fast_tanh(gb);
        const float anew = fmaxf(ham * ed, ab);
        const float e1 = __expf(ham - anew);
        const float e2 = __expf(ab - anew);
        const float ede1 = ed * e1;
        hn  = fmaf(hn, ede1, z * e2);
        hd  = fmaf(hd, ede1, e2);
        ham = anew;
        hres = fast_tanh(hn / hd);
      }
      hl[w][hloc + 4] = hres;
    }
    __syncthreads();

    xa = nxa; xb = nxb; xc = nxc;
  }

  // ---- final outputs --------------------------------------------------------
  {
    const float2 s2 = *(const float2*)(s_in + cellbase);
    *(float2*)(out + OUT_S  + cellbase) = s2;
    *(float2*)(out + OUT_N  + cellbase) = make_float2(nst[0], nst[1]);
    *(float2*)(out + OUT_D  + cellbase) = make_float2(dst[0], dst[1]);
    *(float2*)(out + OUT_H  + cellbase) = make_float2(hv[0], hv[1]);
    *(float2*)(out + OUT_AM + cellbase) = make_float2(amst[0], amst[1]);
  }
}

// ---------------------------------------------------------------------------
// out[b][o] = dot(h_flat[b], o_w[o]) + o_b[o].  Block = one o (1000 blocks);
// thread t covers cols [t*32, t*32+32); 32 per-b accumulators -> butterfly.
// ---------------------------------------------------------------------------
__global__ void __launch_bounds__(256) out_kernel(const float* __restrict__ outH,
                                                  const float* __restrict__ ow,
                                                  const float* __restrict__ ob,
                                                  float* __restrict__ out) {
  const int o   = blockIdx.x;
  const int tid = (int)threadIdx.x;
  const int wv  = tid >> 6;
  const int lane = tid & 63;

  float4 wr[8];
  {
    const float4* wq = (const float4*)(ow + (size_t)o * 8192 + tid * 32);
#pragma unroll
    for (int k = 0; k < 8; ++k) wr[k] = wq[k];
  }
  float acc[32];
#pragma unroll
  for (int b = 0; b < 32; ++b) {
    const float4* hq = (const float4*)(outH + (size_t)b * 8192 + tid * 32);
    float s0 = 0.f, s1 = 0.f;
#pragma unroll
    for (int k = 0; k < 8; k += 2) {
      const float4 h0 = hq[k], h1 = hq[k + 1];
      s0 = fmaf(h0.x, wr[k].x, s0);     s0 = fmaf(h0.y, wr[k].y, s0);
      s0 = fmaf(h0.z, wr[k].z, s0);     s0 = fmaf(h0.w, wr[k].w, s0);
      s1 = fmaf(h1.x, wr[k+1].x, s1);   s1 = fmaf(h1.y, wr[k+1].y, s1);
      s1 = fmaf(h1.z, wr[k+1].z, s1);   s1 = fmaf(h1.w, wr[k+1].w, s1);
    }
    acc[b] = s0 + s1;
  }
#pragma unroll
  for (int m = 1; m <= 32; m <<= 1)
#pragma unroll
    for (int b = 0; b < 32; ++b) acc[b] += __shfl_xor(acc[b], m);

  __shared__ float red[4][32];
  if (lane < 32) red[wv][lane] = acc[lane];
  __syncthreads();
  if (tid < 32)
    out[tid * 1000 + o] = red[0][tid] + red[1][tid] + red[2][tid] + red[3][tid] + ob[o];
}

// ---------------------------------------------------------------------------
extern "C" void kernel_launch(void* const* d_in, const int* in_sizes, int n_in,
                              void* d_out, int out_size, void* d_ws, size_t ws_size,
                              hipStream_t stream) {
  (void)in_sizes; (void)n_in; (void)out_size; (void)ws_size;
  const float* x   = (const float*)d_in[0];
  const float* s   = (const float*)d_in[1];
  const float* n_  = (const float*)d_in[2];
  const float* dd  = (const float*)d_in[3];
  const float* h   = (const float*)d_in[4];
  const float* am  = (const float*)d_in[5];
  const float* xrw = (const float*)d_in[6];
  const float* gw  = (const float*)d_in[7];
  const float* ggm = (const float*)d_in[9];
  const float* gbt = (const float*)d_in[10];
  const float* uw  = (const float*)d_in[11];
  const float* ugm = (const float*)d_in[13];
  const float* ubt = (const float*)d_in[14];
  const float* aw  = (const float*)d_in[15];
  const float* agm = (const float*)d_in[17];
  const float* abt = (const float*)d_in[18];
  const float* dw  = (const float*)d_in[19];
  const float* dgm = (const float*)d_in[21];
  const float* dbt = (const float*)d_in[22];
  const float* ow  = (const float*)d_in[23];
  const float* ob  = (const float*)d_in[24];
  float* out = (float*)d_out;
  float* ws  = (float*)d_ws;

  float* XR     = ws + XR_OFF;
  float* wT     = ws + WT_OFF;
  float* wpack  = ws + WPK_OFF;
  float* acc3   = ws + ACC_OFF;
  float* slots2 = ws + SL2_OFF;
  unsigned* cnt = (unsigned*)(ws + CNT_OFF);
  unsigned long long* stt = (unsigned long long*)(ws + STT_OFF);

  prep_kernel<<<dim3(512), dim3(256), 0, stream>>>(xrw, wT, gw, aw, dw, uw, wpack, acc3, cnt);
  xr_kernel<<<dim3(256), dim3(256), 0, stream>>>(x, wT, XR);

  void* args[] = { &XR, &wpack, &acc3, &slots2, &cnt, &stt, &s, &n_, &dd, &h, &am,
                   &ggm, &gbt, &ugm, &ubt, &agm, &abt, &dgm, &dbt, &out };
  hipError_t err = hipLaunchCooperativeKernel((void*)scan_kernel, dim3(NBLK + 1), dim3(NTHR),
                                              args, 0, stream);
  if (err != hipSuccess) {
    scan_kernel<<<dim3(NBLK + 1), dim3(NTHR), 0, stream>>>(XR, wpack, acc3, slots2, cnt, stt,
                                                           s, n_, dd, h, am,
                                                           ggm, gbt, ugm, ubt, agm, abt,
                                                           dgm, dbt, out);
  }

  out_kernel<<<dim3(1000), dim3(256), 0, stream>>>(out + OUT_H, ow, ob, out);
}